// Round 11
// baseline (650.736 us; speedup 1.0000x reference)
//
#include <hip/hip_runtime.h>

#define T_LEN 1024
#define B_TOTAL 8192

typedef _Float16 f16x8 __attribute__((ext_vector_type(8)));
typedef _Float16 f16x2 __attribute__((ext_vector_type(2)));
typedef __fp16 fp16x2 __attribute__((ext_vector_type(2)));
typedef float f32x4 __attribute__((ext_vector_type(4)));

__device__ __forceinline__ float fast_tanh(float x) {
    // tanh(x) = 1 - 2/(exp(2x)+1); v_exp_f32 + v_rcp_f32, err ~1e-6.
    float e = __builtin_amdgcn_exp2f(x * 2.8853900817779268f); // 2*log2(e)
    float r = __builtin_amdgcn_rcpf(e + 1.0f);
    return fmaf(-2.0f, r, 1.0f);
}

__device__ __forceinline__ f16x2 pk(float a, float b) {
    const fp16x2 p = __builtin_amdgcn_cvt_pkrtz(a, b); // v_cvt_pkrtz_f16_f32
    union { fp16x2 i; f16x2 o; } u;
    u.i = p;
    return u.o;
}

// 8x tanh + packed f32->f16 (cvt_pkrtz: 2 values/inst, RTZ).
__device__ __forceinline__ f16x8 tanh_pack(const f32x4 lo, const f32x4 hi) {
    f16x8 y;
    ((f16x2*)&y)[0] = pk(fast_tanh(lo[0]), fast_tanh(lo[1]));
    ((f16x2*)&y)[1] = pk(fast_tanh(lo[2]), fast_tanh(lo[3]));
    ((f16x2*)&y)[2] = pk(fast_tanh(hi[0]), fast_tanh(hi[1]));
    ((f16x2*)&y)[3] = pk(fast_tanh(hi[2]), fast_tanh(hi[3]));
    return y;
}

#define MFMA(a, b, c) __builtin_amdgcn_mfma_f32_16x16x32_f16((a), (b), (c), 0, 0, 0)

// DUAL-GROUP single-wave kernel: one wave carries TWO independent 16-batch
// groups (A: bl, B: bl+16 within a 32-batch block). Weights/consts live once
// in shared registers; each group has its own state/accumulators. The two
// groups' dependency chains interleave -> group B's issue fills group A's
// stalls (probe: stall-bound -> big win; issue-bound -> flat).
// Unit-relabeling (round-6-verified): A-row m <- weight row 8*(m>>2)+(m&3)
// (lo) / +4 (hi); lane (bl,g)'s D regs are storage slots {8g+r, 8g+4+r} =
// exactly its next B-fragment k-slots -> no transpose anywhere.
__global__ __launch_bounds__(64, 1) void rnn_dual_kernel(
    const float* __restrict__ x,     const float* __restrict__ h0,
    const float* __restrict__ W_ih0, const float* __restrict__ W_hh0,
    const float* __restrict__ b_ih0, const float* __restrict__ b_hh0,
    const float* __restrict__ W_ih1, const float* __restrict__ W_hh1,
    const float* __restrict__ b_ih1, const float* __restrict__ b_hh1,
    const float* __restrict__ W_out, const float* __restrict__ b_out,
    float* __restrict__ out)
{
    const int lane = threadIdx.x;           // 0..63
    const int bl   = lane & 15;             // batch column (n-index / A-row)
    const int hi   = lane >> 4;             // lane quad g
    const int s0   = hi * 8;                // storage-slot base
    const int gbA  = blockIdx.x * 32 + bl;  // group A batch
    const int gbB  = gbA + 16;              // group B batch

    const int ulo = 8 * (bl >> 2) + (bl & 3); // weight row for A-lo row bl
    const int uhi = ulo + 4;

    // --- shared stationary A fragments (weights, unit-permuted rows) ---
    f16x8 whh0_lo, whh0_hi, wih1_lo, wih1_hi, whh1_lo, whh1_hi, wout_f;
#pragma unroll
    for (int e = 0; e < 8; ++e) {
        whh0_lo[e] = (_Float16)W_hh0[ulo * 32 + s0 + e];
        whh0_hi[e] = (_Float16)W_hh0[uhi * 32 + s0 + e];
        wih1_lo[e] = (_Float16)W_ih1[ulo * 32 + s0 + e];
        wih1_hi[e] = (_Float16)W_ih1[uhi * 32 + s0 + e];
        whh1_lo[e] = (_Float16)W_hh1[ulo * 32 + s0 + e];
        whh1_hi[e] = (_Float16)W_hh1[uhi * 32 + s0 + e];
        wout_f[e]  = (bl == 0) ? (_Float16)W_out[s0 + e] : (_Float16)0.0f;
    }

    // --- shared per-lane D-layout constants ---
    f32x4 c0lo, c0hi, c1lo, c1hi, wi0lo, wi0hi;
#pragma unroll
    for (int r = 0; r < 4; ++r) {
        const int u = s0 + r, uh = s0 + 4 + r;
        c0lo[r] = b_ih0[u]  + b_hh0[u];
        c0hi[r] = b_ih0[uh] + b_hh0[uh];
        c1lo[r] = b_ih1[u]  + b_hh1[u];
        c1hi[r] = b_ih1[uh] + b_hh1[uh];
        wi0lo[r] = W_ih0[u];
        wi0hi[r] = W_ih0[uh];
    }
    const float bo = b_out[0];
    const f32x4 zero4 = {0.f, 0.f, 0.f, 0.f};

    // --- per-group state fragments ---
    f16x8 Y1A, Y2A, Y1B, Y2B;
#pragma unroll
    for (int e = 0; e < 8; ++e) {
        Y1A[e] = (_Float16)h0[(size_t)gbA * 32 + s0 + e];
        Y2A[e] = (_Float16)h0[(size_t)(B_TOTAL + gbA) * 32 + s0 + e];
        Y1B[e] = (_Float16)h0[(size_t)gbB * 32 + s0 + e];
        Y2B[e] = (_Float16)h0[(size_t)(B_TOTAL + gbB) * 32 + s0 + e];
    }

    const float* xpA = x + (size_t)gbA * T_LEN;
    const float* xpB = x + (size_t)gbB * T_LEN;
    float* ypA = out + (size_t)gbA * T_LEN;
    float* ypB = out + (size_t)gbB * T_LEN;

    float4 xqA = *(const float4*)(xpA);
    float4 xqB = *(const float4*)(xpB);

    for (int t = 0; t < T_LEN; t += 4) {
        const float4 xqnA = (t + 4 < T_LEN) ? *(const float4*)(xpA + t + 4) : xqA;
        const float4 xqnB = (t + 4 < T_LEN) ? *(const float4*)(xpB + t + 4) : xqB;
        float yA0, yA1, yA2, yA3, yB0, yB1, yB2, yB3;
#pragma unroll
        for (int u = 0; u < 4; ++u) {
            const float xtA = (u == 0) ? xqA.x : (u == 1) ? xqA.y : (u == 2) ? xqA.z : xqA.w;
            const float xtB = (u == 0) ? xqB.x : (u == 1) ? xqB.y : (u == 2) ? xqB.z : xqB.w;

            // ---- layer 1 (both groups): d1 = W_hh0 . h1 + (c0 + wih0*x) ----
            f32x4 pAlo, pAhi, pBlo, pBhi;
#pragma unroll
            for (int r = 0; r < 4; ++r) {
                pAlo[r] = fmaf(xtA, wi0lo[r], c0lo[r]);
                pAhi[r] = fmaf(xtA, wi0hi[r], c0hi[r]);
                pBlo[r] = fmaf(xtB, wi0lo[r], c0lo[r]);
                pBhi[r] = fmaf(xtB, wi0hi[r], c0hi[r]);
            }
            const f32x4 d1Alo = MFMA(whh0_lo, Y1A, pAlo);
            const f32x4 d1Ahi = MFMA(whh0_hi, Y1A, pAhi);
            const f32x4 d1Blo = MFMA(whh0_lo, Y1B, pBlo);
            const f32x4 d1Bhi = MFMA(whh0_hi, Y1B, pBhi);
            // layer-2 recurrent halves on OLD h2 (independent of d1)
            const f32x4 d2aAlo = MFMA(whh1_lo, Y2A, c1lo);
            const f32x4 d2aAhi = MFMA(whh1_hi, Y2A, c1hi);
            const f32x4 d2aBlo = MFMA(whh1_lo, Y2B, c1lo);
            const f32x4 d2aBhi = MFMA(whh1_hi, Y2B, c1hi);

            // ---- h1 = tanh(d1), packed to f16 (A and B interleave) ----
            Y1A = tanh_pack(d1Alo, d1Ahi);
            Y1B = tanh_pack(d1Blo, d1Bhi);

            // ---- layer 2 completion on NEW h1 ----
            const f32x4 d2Alo = MFMA(wih1_lo, Y1A, d2aAlo);
            const f32x4 d2Ahi = MFMA(wih1_hi, Y1A, d2aAhi);
            const f32x4 d2Blo = MFMA(wih1_lo, Y1B, d2aBlo);
            const f32x4 d2Bhi = MFMA(wih1_hi, Y1B, d2aBhi);

            Y2A = tanh_pack(d2Alo, d2Ahi);
            Y2B = tanh_pack(d2Blo, d2Bhi);

            // ---- y head: W_out in A-row 0 -> y[bl] = D[m=0][bl] (hi==0) ----
            const f32x4 d3A = MFMA(wout_f, Y2A, zero4);
            const f32x4 d3B = MFMA(wout_f, Y2B, zero4);
            const float yvA = d3A[0] + bo;
            const float yvB = d3B[0] + bo;
            if (u == 0) { yA0 = yvA; yB0 = yvB; }
            else if (u == 1) { yA1 = yvA; yB1 = yvB; }
            else if (u == 2) { yA2 = yvA; yB2 = yvB; }
            else { yA3 = yvA; yB3 = yvB; }
        }
        if (hi == 0) {
            float4 yoA; yoA.x = yA0; yoA.y = yA1; yoA.z = yA2; yoA.w = yA3;
            *(float4*)(ypA + t) = yoA;
            float4 yoB; yoB.x = yB0; yoB.y = yB1; yoB.z = yB2; yoB.w = yB3;
            *(float4*)(ypB + t) = yoB;
        }
        xqA = xqnA;
        xqB = xqnB;
    }

    // --- final hidden states from f16 state (one extra 2^-11 rounding) ---
    float* hs = out + (size_t)B_TOTAL * T_LEN;
#pragma unroll
    for (int e = 0; e < 8; ++e) {
        hs[(size_t)gbA * 32 + s0 + e]             = (float)Y1A[e];
        hs[(size_t)(B_TOTAL + gbA) * 32 + s0 + e] = (float)Y2A[e];
        hs[(size_t)gbB * 32 + s0 + e]             = (float)Y1B[e];
        hs[(size_t)(B_TOTAL + gbB) * 32 + s0 + e] = (float)Y2B[e];
    }
}

extern "C" void kernel_launch(void* const* d_in, const int* in_sizes, int n_in,
                              void* d_out, int out_size, void* d_ws, size_t ws_size,
                              hipStream_t stream) {
    const float* x     = (const float*)d_in[0];
    const float* h0    = (const float*)d_in[1];
    const float* W_ih0 = (const float*)d_in[2];
    const float* W_hh0 = (const float*)d_in[3];
    const float* b_ih0 = (const float*)d_in[4];
    const float* b_hh0 = (const float*)d_in[5];
    const float* W_ih1 = (const float*)d_in[6];
    const float* W_hh1 = (const float*)d_in[7];
    const float* b_ih1 = (const float*)d_in[8];
    const float* b_hh1 = (const float*)d_in[9];
    const float* W_out = (const float*)d_in[10];
    const float* b_out = (const float*)d_in[11];
    float* out = (float*)d_out;

    dim3 grid(B_TOTAL / 32); // 256 blocks x 1 wave; 2 groups of 16 batches each
    dim3 block(64);
    rnn_dual_kernel<<<grid, block, 0, stream>>>(x, h0, W_ih0, W_hh0, b_ih0, b_hh0,
                                                W_ih1, W_hh1, b_ih1, b_hh1,
                                                W_out, b_out, out);
}

// Round 12
// 227.677 us; speedup vs baseline: 2.8581x; 2.8581x over previous
//
#include <hip/hip_runtime.h>

#define T_LEN 1024
#define B_TOTAL 8192
#define NITER 256  // T_LEN / 4

typedef _Float16 f16x8 __attribute__((ext_vector_type(8)));
typedef _Float16 f16x2 __attribute__((ext_vector_type(2)));
typedef __fp16 fp16x2 __attribute__((ext_vector_type(2)));
typedef float f32x4 __attribute__((ext_vector_type(4)));

__device__ __forceinline__ float fast_tanh(float x) {
    // tanh(x) = 1 - 2/(exp(2x)+1); v_exp_f32 + v_rcp_f32, err ~1e-6.
    float e = __builtin_amdgcn_exp2f(x * 2.8853900817779268f); // 2*log2(e)
    float r = __builtin_amdgcn_rcpf(e + 1.0f);
    return fmaf(-2.0f, r, 1.0f);
}

__device__ __forceinline__ f16x2 pk(float a, float b) {
    const fp16x2 p = __builtin_amdgcn_cvt_pkrtz(a, b); // v_cvt_pkrtz_f16_f32
    union { fp16x2 i; f16x2 o; } u;
    u.i = p;
    return u.o;
}

// 8x tanh + packed f32->f16 casts (cvt_pkrtz: 2 values/inst).
__device__ __forceinline__ f16x8 tanh_pack(const f32x4 lo, const f32x4 hi) {
    f16x8 y;
    ((f16x2*)&y)[0] = pk(fast_tanh(lo[0]), fast_tanh(lo[1]));
    ((f16x2*)&y)[1] = pk(fast_tanh(lo[2]), fast_tanh(lo[3]));
    ((f16x2*)&y)[2] = pk(fast_tanh(hi[0]), fast_tanh(hi[1]));
    ((f16x2*)&y)[3] = pk(fast_tanh(hi[2]), fast_tanh(hi[3]));
    return y;
}

#define MFMA(a, b, c) __builtin_amdgcn_mfma_f32_16x16x32_f16((a), (b), (c), 0, 0, 0)

// Layer-split pipeline with FORCED SIMD SPREAD: 256-thread blocks = 4 waves =
// the CU's 4 SIMDs (wave i -> SIMD i). Two independent producer/consumer
// pairs per block (wid 0/1 = pair 0 on SIMD 0/1; wid 2/3 = pair 1 on SIMD
// 2/3). Producer: layer-1 recurrence -> 16-slot LDS ring. Consumer: layer-2
// recurrence + y head, lagging 2 iterations (8 steps); 1 block-wide barrier
// per 4-step iteration; ds_read prefetched 1 step ahead -> handoff latency
// fully off the serial chain (round-8 scheme; round 8's flat result is
// attributed to both waves of its 128-thread blocks sharing a SIMD).
// Unit-relabeling (round-6-verified): A-row m <- weight row 8*(m>>2)+(m&3)
// (lo) / +4 (hi); lane (bl,g)'s D regs are storage slots {8g+r, 8g+4+r} =
// exactly its next B-fragment k-slots -> no transpose anywhere.
__global__ __launch_bounds__(256, 1) void rnn_pair_kernel(
    const float* __restrict__ x,     const float* __restrict__ h0,
    const float* __restrict__ W_ih0, const float* __restrict__ W_hh0,
    const float* __restrict__ b_ih0, const float* __restrict__ b_hh0,
    const float* __restrict__ W_ih1, const float* __restrict__ W_hh1,
    const float* __restrict__ b_ih1, const float* __restrict__ b_hh1,
    const float* __restrict__ W_out, const float* __restrict__ b_out,
    float* __restrict__ out)
{
    // [pair][slot][row][40 halves] : 80B row stride, <=2-way alias (free).
    __shared__ __align__(16) _Float16 ring[2][16][16][40];

    const int tid  = threadIdx.x;
    const int wid  = tid >> 6;
    const int p    = wid >> 1;            // pair 0/1
    const int role = wid & 1;             // 0 = producer, 1 = consumer
    const int lane = tid & 63;
    const int bl   = lane & 15;           // batch column (n-index / A-row)
    const int hi   = lane >> 4;           // lane quad g
    const int s0   = hi * 8;              // storage-slot base
    const int gb   = blockIdx.x * 32 + p * 16 + bl;

    const int ulo = 8 * (bl >> 2) + (bl & 3); // weight row for A-lo row bl
    const int uhi = ulo + 4;

    if (role == 0) {
        // ================= producer: layer 1 =================
        f16x8 whh0_lo, whh0_hi;
#pragma unroll
        for (int e = 0; e < 8; ++e) {
            whh0_lo[e] = (_Float16)W_hh0[ulo * 32 + s0 + e];
            whh0_hi[e] = (_Float16)W_hh0[uhi * 32 + s0 + e];
        }
        f32x4 c0lo, c0hi, wi0lo, wi0hi;
#pragma unroll
        for (int r = 0; r < 4; ++r) {
            const int u = s0 + r, uh = s0 + 4 + r;
            c0lo[r] = b_ih0[u]  + b_hh0[u];
            c0hi[r] = b_ih0[uh] + b_hh0[uh];
            wi0lo[r] = W_ih0[u];
            wi0hi[r] = W_ih0[uh];
        }
        f16x8 Y1;
#pragma unroll
        for (int e = 0; e < 8; ++e)
            Y1[e] = (_Float16)h0[(size_t)gb * 32 + s0 + e];

        const float* xp = x + (size_t)gb * T_LEN;
        float4 xq = *(const float4*)(xp);

        for (int m = 0; m < NITER + 2; ++m) {
            if (m < NITER) {
                const int t = m * 4;
                const float4 xqn = (t + 4 < T_LEN) ? *(const float4*)(xp + t + 4) : xq;
#pragma unroll
                for (int u = 0; u < 4; ++u) {
                    const float xt = (u == 0) ? xq.x : (u == 1) ? xq.y : (u == 2) ? xq.z : xq.w;
                    f32x4 plo, phi;
#pragma unroll
                    for (int r = 0; r < 4; ++r) {
                        plo[r] = fmaf(xt, wi0lo[r], c0lo[r]);
                        phi[r] = fmaf(xt, wi0hi[r], c0hi[r]);
                    }
                    const f32x4 d1lo = MFMA(whh0_lo, Y1, plo);
                    const f32x4 d1hi = MFMA(whh0_hi, Y1, phi);
                    const f16x8 Y1n = tanh_pack(d1lo, d1hi);
                    *(f16x8*)&ring[p][((m & 3) << 2) + u][bl][s0] = Y1n;
                    Y1 = Y1n;
                }
                xq = xqn;
            }
            asm volatile("s_waitcnt lgkmcnt(0)" ::: "memory");
            __builtin_amdgcn_s_barrier();
            asm volatile("" ::: "memory");
        }
        // final h1 -> h_state[0] (from f16 state; +2^-11 one-time rounding)
        float* hs = out + (size_t)B_TOTAL * T_LEN;
#pragma unroll
        for (int e = 0; e < 8; ++e)
            hs[(size_t)gb * 32 + s0 + e] = (float)Y1[e];
    } else {
        // ================= consumer: layer 2 + head (lag 8 steps) ==========
        f16x8 wih1_lo, wih1_hi, whh1_lo, whh1_hi, wout_f;
#pragma unroll
        for (int e = 0; e < 8; ++e) {
            wih1_lo[e] = (_Float16)W_ih1[ulo * 32 + s0 + e];
            wih1_hi[e] = (_Float16)W_ih1[uhi * 32 + s0 + e];
            whh1_lo[e] = (_Float16)W_hh1[ulo * 32 + s0 + e];
            whh1_hi[e] = (_Float16)W_hh1[uhi * 32 + s0 + e];
            wout_f[e]  = (bl == 0) ? (_Float16)W_out[s0 + e] : (_Float16)0.0f;
        }
        f32x4 c1lo, c1hi;
#pragma unroll
        for (int r = 0; r < 4; ++r) {
            const int u = s0 + r, uh = s0 + 4 + r;
            c1lo[r] = b_ih1[u]  + b_hh1[u];
            c1hi[r] = b_ih1[uh] + b_hh1[uh];
        }
        const float bo = b_out[0];
        const f32x4 zero4 = {0.f, 0.f, 0.f, 0.f};

        f16x8 Y2;
#pragma unroll
        for (int e = 0; e < 8; ++e)
            Y2[e] = (_Float16)h0[(size_t)(B_TOTAL + gb) * 32 + s0 + e];

        float* yp = out + (size_t)gb * T_LEN;
        f16x8 Y1pre; // preloaded h1 for the current step

        for (int m = 0; m < NITER + 2; ++m) {
            if (m >= 2) {
                const int j = m - 2;     // producer iteration being consumed
                const int t = j * 4;
                if (j == 0)
                    Y1pre = *(const f16x8*)&ring[p][0][bl][s0];
                float yq0, yq1, yq2, yq3;
#pragma unroll
                for (int u = 0; u < 4; ++u) {
                    // recurrent half on own (old) h2 first
                    f32x4 d2lo = MFMA(whh1_lo, Y2, c1lo);
                    f32x4 d2hi = MFMA(whh1_hi, Y2, c1hi);

                    // prefetch next step's h1 (written >=1 iteration ago)
                    const int ns = (u < 3) ? ((j & 3) << 2) + u + 1
                                           : (((j + 1) & 3) << 2);
                    const f16x8 Y1nx = *(const f16x8*)&ring[p][ns][bl][s0];

                    d2lo = MFMA(wih1_lo, Y1pre, d2lo);
                    d2hi = MFMA(wih1_hi, Y1pre, d2hi);
                    const f16x8 Y2n = tanh_pack(d2lo, d2hi);

                    // y head: W_out in A-row 0 -> y[bl] = D[m=0][bl]
                    const f32x4 d3 = MFMA(wout_f, Y2n, zero4);
                    const float yv = d3[0] + bo;
                    if (u == 0) yq0 = yv; else if (u == 1) yq1 = yv; else if (u == 2) yq2 = yv; else yq3 = yv;

                    Y2 = Y2n;
                    Y1pre = Y1nx;
                }
                if (hi == 0) {
                    float4 yo; yo.x = yq0; yo.y = yq1; yo.z = yq2; yo.w = yq3;
                    *(float4*)(yp + t) = yo;
                }
            }
            __builtin_amdgcn_s_barrier();
            asm volatile("" ::: "memory");
        }
        // final h2 -> h_state[1] (from f16 state)
        float* hs = out + (size_t)B_TOTAL * T_LEN;
#pragma unroll
        for (int e = 0; e < 8; ++e)
            hs[(size_t)(B_TOTAL + gb) * 32 + s0 + e] = (float)Y2[e];
    }
}

extern "C" void kernel_launch(void* const* d_in, const int* in_sizes, int n_in,
                              void* d_out, int out_size, void* d_ws, size_t ws_size,
                              hipStream_t stream) {
    const float* x     = (const float*)d_in[0];
    const float* h0    = (const float*)d_in[1];
    const float* W_ih0 = (const float*)d_in[2];
    const float* W_hh0 = (const float*)d_in[3];
    const float* b_ih0 = (const float*)d_in[4];
    const float* b_hh0 = (const float*)d_in[5];
    const float* W_ih1 = (const float*)d_in[6];
    const float* W_hh1 = (const float*)d_in[7];
    const float* b_ih1 = (const float*)d_in[8];
    const float* b_hh1 = (const float*)d_in[9];
    const float* W_out = (const float*)d_in[10];
    const float* b_out = (const float*)d_in[11];
    float* out = (float*)d_out;

    dim3 grid(B_TOTAL / 32); // 256 blocks x 4 waves (2 P/C pairs) = 1024 waves
    dim3 block(256);
    rnn_pair_kernel<<<grid, block, 0, stream>>>(x, h0, W_ih0, W_hh0, b_ih0, b_hh0,
                                                W_ih1, W_hh1, b_ih1, b_hh1,
                                                W_out, b_out, out);
}

// Round 13
// 215.883 us; speedup vs baseline: 3.0143x; 1.0546x over previous
//
#include <hip/hip_runtime.h>

#define T_LEN 1024
#define B_TOTAL 8192
#define NOUTER 130  // 128 work-outers (8 steps each) + 2 lag

typedef _Float16 f16x8 __attribute__((ext_vector_type(8)));
typedef _Float16 f16x2 __attribute__((ext_vector_type(2)));
typedef __fp16 fp16x2 __attribute__((ext_vector_type(2)));
typedef float f32x4 __attribute__((ext_vector_type(4)));

__device__ __forceinline__ float fast_tanh(float x) {
    // tanh(x) = 1 - 2/(exp(2x)+1); v_exp_f32 + v_rcp_f32, err ~1e-6.
    float e = __builtin_amdgcn_exp2f(x * 2.8853900817779268f); // 2*log2(e)
    float r = __builtin_amdgcn_rcpf(e + 1.0f);
    return fmaf(-2.0f, r, 1.0f);
}

__device__ __forceinline__ f16x2 pk(float a, float b) {
    const fp16x2 p = __builtin_amdgcn_cvt_pkrtz(a, b); // v_cvt_pkrtz_f16_f32
    union { fp16x2 i; f16x2 o; } u;
    u.i = p;
    return u.o;
}

// 8x tanh + packed f32->f16 casts (cvt_pkrtz: 2 values/inst).
__device__ __forceinline__ f16x8 tanh_pack(const f32x4 lo, const f32x4 hi) {
    f16x8 y;
    ((f16x2*)&y)[0] = pk(fast_tanh(lo[0]), fast_tanh(lo[1]));
    ((f16x2*)&y)[1] = pk(fast_tanh(lo[2]), fast_tanh(lo[3]));
    ((f16x2*)&y)[2] = pk(fast_tanh(hi[0]), fast_tanh(hi[1]));
    ((f16x2*)&y)[3] = pk(fast_tanh(hi[2]), fast_tanh(hi[3]));
    return y;
}

#define MFMA(a, b, c) __builtin_amdgcn_mfma_f32_16x16x32_f16((a), (b), (c), 0, 0, 0)

// Round-12 structure (4 waves/block = 4 SIMDs, 2 producer/consumer pairs,
// 32 batches/block, 256 blocks) with overhead squeeze:
//  - 32-slot LDS ring (4 quarters of 8 steps); barrier once per 8 steps.
//  - consumer lags 2 outers (16 steps); reads quarter (k-2)&3, prefetches
//    into (k-1)&3; producer writes k&3 -> all distinct, race-free by
//    barrier ordering alone.
//  - unrolled 8-step bodies: every ds access = base + immediate offset.
//  - consumer layer-2 MFMAs de-chained (independent accumulators + v_add).
// Unit-relabeling (round-6-verified): A-row m <- weight row 8*(m>>2)+(m&3)
// (lo) / +4 (hi); lane (bl,g)'s D regs are storage slots {8g+r, 8g+4+r} =
// exactly its next B-fragment k-slots -> no transpose anywhere.
__global__ __launch_bounds__(256, 1) void rnn_pair_kernel(
    const float* __restrict__ x,     const float* __restrict__ h0,
    const float* __restrict__ W_ih0, const float* __restrict__ W_hh0,
    const float* __restrict__ b_ih0, const float* __restrict__ b_hh0,
    const float* __restrict__ W_ih1, const float* __restrict__ W_hh1,
    const float* __restrict__ b_ih1, const float* __restrict__ b_hh1,
    const float* __restrict__ W_out, const float* __restrict__ b_out,
    float* __restrict__ out)
{
    // [pair][slot(32)][row(16)][40 halves]: 80B rows (<=2-way alias, free),
    // slot stride 1280B, quarter stride 10240B. Total 80KB.
    __shared__ __align__(16) _Float16 ring[2][32][16][40];

    const int tid  = threadIdx.x;
    const int wid  = tid >> 6;
    const int p    = wid >> 1;            // pair 0/1
    const int role = wid & 1;             // 0 = producer, 1 = consumer
    const int lane = tid & 63;
    const int bl   = lane & 15;           // batch column (n-index / A-row)
    const int hi   = lane >> 4;           // lane quad g
    const int s0   = hi * 8;              // storage-slot base
    const int gb   = blockIdx.x * 32 + p * 16 + bl;

    const int ulo = 8 * (bl >> 2) + (bl & 3); // weight row for A-lo row bl
    const int uhi = ulo + 4;

    _Float16* const B0 = &ring[p][0][bl][s0]; // per-lane ring base
    // quarter stride = 5120 halves, step stride = 640 halves

    if (role == 0) {
        // ================= producer: layer 1 =================
        f16x8 whh0_lo, whh0_hi;
#pragma unroll
        for (int e = 0; e < 8; ++e) {
            whh0_lo[e] = (_Float16)W_hh0[ulo * 32 + s0 + e];
            whh0_hi[e] = (_Float16)W_hh0[uhi * 32 + s0 + e];
        }
        f32x4 c0lo, c0hi, wi0lo, wi0hi;
#pragma unroll
        for (int r = 0; r < 4; ++r) {
            const int u = s0 + r, uh = s0 + 4 + r;
            c0lo[r] = b_ih0[u]  + b_hh0[u];
            c0hi[r] = b_ih0[uh] + b_hh0[uh];
            wi0lo[r] = W_ih0[u];
            wi0hi[r] = W_ih0[uh];
        }
        f16x8 Y1;
#pragma unroll
        for (int e = 0; e < 8; ++e)
            Y1[e] = (_Float16)h0[(size_t)gb * 32 + s0 + e];

        const float* xp = x + (size_t)gb * T_LEN;
        float4 xc0 = *(const float4*)(xp);
        float4 xc1 = *(const float4*)(xp + 4);

        for (int k = 0; k < NOUTER; ++k) {
            if (k < 128) {
                // prefetch next outer's x (8 steps ahead; vmcnt in flight)
                const int tn = (k < 127) ? (k + 1) * 8 : 0;
                const float4 xn0 = *(const float4*)(xp + tn);
                const float4 xn1 = *(const float4*)(xp + tn + 4);

                _Float16* const wb = B0 + (k & 3) * 5120;
#pragma unroll
                for (int i = 0; i < 8; ++i) {
                    const float xt =
                        (i == 0) ? xc0.x : (i == 1) ? xc0.y : (i == 2) ? xc0.z :
                        (i == 3) ? xc0.w : (i == 4) ? xc1.x : (i == 5) ? xc1.y :
                        (i == 6) ? xc1.z : xc1.w;
                    f32x4 plo, phi;
#pragma unroll
                    for (int r = 0; r < 4; ++r) {
                        plo[r] = fmaf(xt, wi0lo[r], c0lo[r]);
                        phi[r] = fmaf(xt, wi0hi[r], c0hi[r]);
                    }
                    const f32x4 d1lo = MFMA(whh0_lo, Y1, plo);
                    const f32x4 d1hi = MFMA(whh0_hi, Y1, phi);
                    const f16x8 Y1n = tanh_pack(d1lo, d1hi);
                    *(f16x8*)(wb + i * 640) = Y1n; // immediate ds offset
                    Y1 = Y1n;
                }
                xc0 = xn0;
                xc1 = xn1;
            }
            asm volatile("s_waitcnt lgkmcnt(0)" ::: "memory");
            __builtin_amdgcn_s_barrier();
            asm volatile("" ::: "memory");
        }
        // final h1 -> h_state[0] (from f16 state)
        float* hs = out + (size_t)B_TOTAL * T_LEN;
#pragma unroll
        for (int e = 0; e < 8; ++e)
            hs[(size_t)gb * 32 + s0 + e] = (float)Y1[e];
    } else {
        // ================= consumer: layer 2 + head (lag 16 steps) =========
        f16x8 wih1_lo, wih1_hi, whh1_lo, whh1_hi, wout_f;
#pragma unroll
        for (int e = 0; e < 8; ++e) {
            wih1_lo[e] = (_Float16)W_ih1[ulo * 32 + s0 + e];
            wih1_hi[e] = (_Float16)W_ih1[uhi * 32 + s0 + e];
            whh1_lo[e] = (_Float16)W_hh1[ulo * 32 + s0 + e];
            whh1_hi[e] = (_Float16)W_hh1[uhi * 32 + s0 + e];
            wout_f[e]  = (bl == 0) ? (_Float16)W_out[s0 + e] : (_Float16)0.0f;
        }
        f32x4 c1lo, c1hi;
#pragma unroll
        for (int r = 0; r < 4; ++r) {
            const int u = s0 + r, uh = s0 + 4 + r;
            c1lo[r] = b_ih1[u]  + b_hh1[u];
            c1hi[r] = b_ih1[uh] + b_hh1[uh];
        }
        const float bo = b_out[0];
        const f32x4 zero4 = {0.f, 0.f, 0.f, 0.f};

        f16x8 Y2;
#pragma unroll
        for (int e = 0; e < 8; ++e)
            Y2[e] = (_Float16)h0[(size_t)(B_TOTAL + gb) * 32 + s0 + e];

        float* yp = out + (size_t)gb * T_LEN;
        f16x8 Y1pre;

        for (int k = 0; k < NOUTER; ++k) {
            if (k >= 2) {
                const int j = k - 2;     // producer outer being consumed
                const _Float16* const rb  = B0 + (j & 3) * 5120;
                const _Float16* const rbn = B0 + ((j + 1) & 3) * 5120;
                if (j == 0)
                    Y1pre = *(const f16x8*)rb; // slot 0, one-time
                float yv[8];
#pragma unroll
                for (int i = 0; i < 8; ++i) {
                    // independent accumulators (no MFMA C-chain)
                    const f32x4 d2alo = MFMA(whh1_lo, Y2, c1lo);
                    const f32x4 d2ahi = MFMA(whh1_hi, Y2, c1hi);
                    const f32x4 d2blo = MFMA(wih1_lo, Y1pre, zero4);
                    const f32x4 d2bhi = MFMA(wih1_hi, Y1pre, zero4);

                    // prefetch next step's h1 (immediate ds offset;
                    // i==7 crosses into quarter (j+1)&3, written last outer)
                    const f16x8 Y1nx = (i < 7)
                        ? *(const f16x8*)(rb + (i + 1) * 640)
                        : *(const f16x8*)rbn;

                    const f32x4 slo = d2alo + d2blo;
                    const f32x4 shi = d2ahi + d2bhi;
                    const f16x8 Y2n = tanh_pack(slo, shi);

                    // y head: W_out in A-row 0 -> y[bl] = D[m=0][bl]
                    const f32x4 d3 = MFMA(wout_f, Y2n, zero4);
                    yv[i] = d3[0] + bo;

                    Y2 = Y2n;
                    Y1pre = Y1nx;
                }
                if (hi == 0) {
                    float4 ya; ya.x = yv[0]; ya.y = yv[1]; ya.z = yv[2]; ya.w = yv[3];
                    float4 yb; yb.x = yv[4]; yb.y = yv[5]; yb.z = yv[6]; yb.w = yv[7];
                    *(float4*)(yp + j * 8)     = ya;
                    *(float4*)(yp + j * 8 + 4) = yb;
                }
            }
            __builtin_amdgcn_s_barrier();
            asm volatile("" ::: "memory");
        }
        // final h2 -> h_state[1] (from f16 state)
        float* hs = out + (size_t)B_TOTAL * T_LEN;
#pragma unroll
        for (int e = 0; e < 8; ++e)
            hs[(size_t)(B_TOTAL + gb) * 32 + s0 + e] = (float)Y2[e];
    }
}

extern "C" void kernel_launch(void* const* d_in, const int* in_sizes, int n_in,
                              void* d_out, int out_size, void* d_ws, size_t ws_size,
                              hipStream_t stream) {
    const float* x     = (const float*)d_in[0];
    const float* h0    = (const float*)d_in[1];
    const float* W_ih0 = (const float*)d_in[2];
    const float* W_hh0 = (const float*)d_in[3];
    const float* b_ih0 = (const float*)d_in[4];
    const float* b_hh0 = (const float*)d_in[5];
    const float* W_ih1 = (const float*)d_in[6];
    const float* W_hh1 = (const float*)d_in[7];
    const float* b_ih1 = (const float*)d_in[8];
    const float* b_hh1 = (const float*)d_in[9];
    const float* W_out = (const float*)d_in[10];
    const float* b_out = (const float*)d_in[11];
    float* out = (float*)d_out;

    dim3 grid(B_TOTAL / 32); // 256 blocks x 4 waves (2 P/C pairs) = 1024 waves
    dim3 block(256);
    rnn_pair_kernel<<<grid, block, 0, stream>>>(x, h0, W_ih0, W_hh0, b_ih0, b_hh0,
                                                W_ih1, W_hh1, b_ih1, b_hh1,
                                                W_out, b_out, out);
}